// Round 9
// baseline (279.019 us; speedup 1.0000x reference)
//
#include <hip/hip_runtime.h>
#include <hip/hip_bf16.h>
#include <cmath>

#define B_     8
#define C_     512
#define N_     1024
#define HEADS_ 8
#define HD_    64
#define INST_  64   // B_ * HEADS_

typedef short     v8s __attribute__((ext_vector_type(8)));
typedef _Float16  v8h __attribute__((ext_vector_type(8)));
typedef float    v16f __attribute__((ext_vector_type(16)));
typedef unsigned short ushort_t;
typedef unsigned int   uint_t;

__device__ inline ushort_t f2h(float x) {
    _Float16 h = (_Float16)x;
    ushort_t r; __builtin_memcpy(&r, &h, 2); return r;
}
// packed f32x2 -> bf16x2 (v_cvt_pk_bf16_f32); low short = .x
__device__ inline uint_t pkbf(float a, float b) {
    __hip_bfloat162 p = __float22bfloat162_rn(make_float2(a, b));
    uint_t r; __builtin_memcpy(&r, &p, 4); return r;
}

// ---------------------------------------------------------------------------
// Kernel 0: unified transpose + fp16-convert prep (unchanged from R8).
//  z in [0,3): w[which][c][d] -> wt[which*512+d][c] fp16
//  z in [3,11): x[b][c][n]    -> xt[b*1024+n][c]    fp16
// ---------------------------------------------------------------------------
__global__ __launch_bounds__(256) void prep_kernel(
    const float* __restrict__ x,
    const float* __restrict__ wq, const float* __restrict__ wk,
    const float* __restrict__ wv,
    uint_t* __restrict__ wt, uint_t* __restrict__ xt)
{
    __shared__ uint_t LH[64 * 32];
    const int z = blockIdx.z;
    const float* src;
    int srcStride;
    size_t outRow0;
    uint_t* oh;
    if (z < 3) {
        if (blockIdx.x >= 8) return;
        src = (z == 0) ? wq : (z == 1) ? wk : wv;
        srcStride = 512;
        outRow0 = (size_t)z * 512 + blockIdx.x * 64;
        oh = wt;
    } else {
        int b = z - 3;
        src = x + (size_t)b * C_ * N_;
        srcStride = 1024;
        outRow0 = (size_t)b * 1024 + blockIdx.x * 64;
        oh = xt;
    }
    const int d0 = blockIdx.x * 64;
    const int c0 = blockIdx.y * 64;
    const int t  = threadIdx.x;

    #pragma unroll
    for (int rep = 0; rep < 2; ++rep) {
        int idx = rep * 256 + t;
        int cp  = idx >> 4;
        int dq  = idx & 15;
        float4 fa = *(const float4*)&src[(size_t)(c0 + 2 * cp) * srcStride + d0 + dq * 4];
        float4 fb = *(const float4*)&src[(size_t)(c0 + 2 * cp + 1) * srcStride + d0 + dq * 4];
        float aa[4] = {fa.x, fa.y, fa.z, fa.w};
        float bb[4] = {fb.x, fb.y, fb.z, fb.w};
        #pragma unroll
        for (int j = 0; j < 4; ++j) {
            int d_l = dq * 4 + j;
            LH[d_l * 32 + (cp ^ (d_l & 31))] =
                (uint_t)f2h(aa[j]) | ((uint_t)f2h(bb[j]) << 16);
        }
    }
    __syncthreads();

    const int d_l = t >> 2;
    const int wq4 = (t & 3) * 8;
    uint_t vh[8];
    #pragma unroll
    for (int i = 0; i < 8; ++i)
        vh[i] = LH[d_l * 32 + ((wq4 + i) ^ (d_l & 31))];
    size_t base = (outRow0 + d_l) * 256 + c0 / 2 + wq4;
    *(uint4*)&oh[base]     = *(uint4*)&vh[0];
    *(uint4*)&oh[base + 4] = *(uint4*)&vh[4];
}

// ---------------------------------------------------------------------------
// Kernel 1: MFMA QKV projection, fp16. Tile 64 tok x 128 d (grid 128x12 =
// 1536 blocks, ~6/CU). Single LDS buffer + 2-deep register prefetch:
// store(k+1)'s vmcnt wait covers loads issued two compute phases earlier.
// ---------------------------------------------------------------------------
__global__ __launch_bounds__(256) void proj_kernel(
    const _Float16* __restrict__ xt, const _Float16* __restrict__ wt,
    const float* __restrict__ bq, const float* __restrict__ bk,
    const float* __restrict__ bv,
    ushort_t* __restrict__ qf, ushort_t* __restrict__ kf,
    ushort_t* __restrict__ vt)
{
    __shared__ _Float16 POOL[8192];    // 16 KB (main loop 12 KB; V-epi 16 KB)
    _Float16* As = POOL;               // [64 tok][4 groups x 8]
    _Float16* Bs = POOL + 2048;        // [128 d][4 groups x 8]

    const int tok0  = blockIdx.x * 64;
    const int b     = tok0 >> 10;
    const int ntb   = tok0 & 1023;
    const int by    = blockIdx.y;
    const int which = by >> 2;                       // 0=q,1=k,2=v
    const int nloc0 = (by & 3) * 128;

    const int t   = threadIdx.x;
    const int w   = t >> 6;
    const int l   = t & 63;
    const int l31 = l & 31;
    const int h5  = l >> 5;
    const int wm  = w & 1;                           // tok half (32 each)
    const int wn  = w >> 1;                          // d half (64 each)

    const int g   = t & 3;
    const int r0  = t >> 2;                          // 0..63
    const int swz = g ^ (r0 & 3);

    const _Float16* baseA = xt + (size_t)(tok0 + r0) * 512 + g * 8;
    const _Float16* baseB = wt + (size_t)(which * 512 + nloc0 + r0) * 512 + g * 8;

    v8h pfa[2], pfb[2][2];             // [set], [set][rep]
    auto load_tile = [&](int set, int tile) {
        int k0 = tile * 32;
        pfa[set] = *(const v8h*)(baseA + k0);
        pfb[set][0] = *(const v8h*)(baseB + k0);
        pfb[set][1] = *(const v8h*)(baseB + 32768 + k0);   // +64 rows
    };
    auto store_tile = [&](int set) {
        int soA = (r0 * 4 + swz) * 8;
        *(v8h*)&As[soA] = pfa[set];
        #pragma unroll
        for (int rep = 0; rep < 2; ++rep) {
            int row = rep * 64 + r0;
            int so  = (row * 4 + (g ^ (row & 3))) * 8;
            *(v8h*)&Bs[so] = pfb[set][rep];
        }
    };

    v16f acc[2] = {{}, {}};            // [ns]: 32 tok x 2x32 d

    load_tile(0, 0);
    store_tile(0);
    load_tile(1, 1);
    load_tile(0, 2);
    __syncthreads();

    for (int step = 0; step < 16; ++step) {
        #pragma unroll
        for (int kc = 0; kc < 2; ++kc) {
            int rm = wm * 32 + l31;
            v8h af = *(const v8h*)&As[(rm * 4 + ((kc * 2 + h5) ^ (rm & 3))) * 8];
            v8h bf[2];
            #pragma unroll
            for (int ns = 0; ns < 2; ++ns) {
                int rn = wn * 64 + ns * 32 + l31;
                bf[ns] = *(const v8h*)&Bs[(rn * 4 + ((kc * 2 + h5) ^ (rn & 3))) * 8];
            }
            #pragma unroll
            for (int ns = 0; ns < 2; ++ns)
                acc[ns] = __builtin_amdgcn_mfma_f32_32x32x16_f16(
                    af, bf[ns], acc[ns], 0, 0, 0);
        }

        __syncthreads();                      // tile consumed
        if (step < 15) {
            int set = (step + 1) & 1;
            store_tile(set);                  // vmcnt wait: loads 2 phases old
            if (step + 3 <= 15) load_tile(set, step + 3);
            __syncthreads();                  // writes visible
        }
    }

    // ---- epilogue ----
    if (which < 2) {
        ushort_t* oh = (which == 0) ? qf : kf;
        const float* bias = (which == 0) ? bq : bk;
        #pragma unroll
        for (int ns = 0; ns < 2; ++ns) {
            int d_local = nloc0 + wn * 64 + ns * 32 + l31;
            float bvv  = bias[d_local];
            int head   = d_local >> 6;
            int hd     = d_local & 63;
            size_t pb  = (size_t)(b * HEADS_ + head) * 65536 + hd;
            #pragma unroll
            for (int r = 0; r < 16; ++r) {
                int n = ntb + wm * 32 + (r & 3) + 8 * (r >> 2) + 4 * h5;
                oh[pb + (size_t)n * 64] = f2h(acc[ns][r] + bvv);
            }
        }
    } else {
        float bvv[2];
        #pragma unroll
        for (int ns = 0; ns < 2; ++ns)
            bvv[ns] = bv[nloc0 + wn * 64 + ns * 32 + l31];
        __syncthreads();                 // staging LDS fully consumed
        uint_t* TW = (uint_t*)POOL + w * 1024;   // wave-private 4 KB: [64 hd][16 w]
        #pragma unroll
        for (int ns = 0; ns < 2; ++ns)
            #pragma unroll
            for (int r = 0; r < 16; r += 2) {
                int tok_l = (r & 3) + 8 * (r >> 2) + 4 * h5;   // even
                int hd_l  = ns * 32 + l31;
                TW[hd_l * 16 + ((tok_l >> 1) ^ (hd_l & 15))] =
                    pkbf(acc[ns][r] + bvv[ns], acc[ns][r + 1] + bvv[ns]);
            }
        __syncthreads();
        const int head = (nloc0 + wn * 64) >> 6;
        uint_t* vtu = (uint_t*)vt;
        size_t base = (size_t)(b * HEADS_ + head) * 32768 + (size_t)l * 512
                    + (ntb + wm * 32) / 2;
        // kv-permutation baked into column order: swap bits 1<->2 of word idx
        // within each 8-word (16-token) block.
        #pragma unroll
        for (int c = 0; c < 4; ++c) {
            uint_t wd[4];
            #pragma unroll
            for (int kk = 0; kk < 4; ++kk) {
                int wsx = c * 4 + kk;
                int w3 = wsx & 7;
                int sw = (wsx & ~7) | (w3 & 1) | (((w3 >> 1) & 1) << 2)
                                   | (((w3 >> 2) & 1) << 1);
                wd[kk] = TW[l * 16 + (sw ^ (l & 15))];
            }
            *(uint4*)&vtu[base + c * 4] = *(uint4*)&wd[0];
        }
    }
}

// ---------------------------------------------------------------------------
// Kernel 2: MFMA flash attention, S^T form, fp16 QK^T + bf16 PV.
// Single LDS buffer + 2-deep register prefetch.
// ---------------------------------------------------------------------------
__global__ __launch_bounds__(256) void attn_kernel(
    const ushort_t* __restrict__ qf, const ushort_t* __restrict__ kf,
    const ushort_t* __restrict__ vt, float* __restrict__ out)
{
    __shared__ _Float16 KH[4096];      // K tile [kv][d] fp16, swizzled
    __shared__ ushort_t VT[4096];      // V^T tile [hd][kv-perm] bf16
    __shared__ float    RS[128];

    const int inst  = blockIdx.x;
    const int chunk = blockIdx.y;
    const int t     = threadIdx.x;
    const int w     = t >> 6;
    const int l     = t & 63;
    const int l31   = l & 31;
    const int h5    = l >> 5;

    const ushort_t* Qf = qf + (size_t)inst * 65536;
    const ushort_t* Kf = kf + (size_t)inst * 65536;
    const ushort_t* Vt = vt + (size_t)inst * 65536;

    const int qbase = chunk * 128 + w * 32;

    v8h aq[4];
    #pragma unroll
    for (int ks = 0; ks < 4; ++ks)
        aq[ks] = *(const v8h*)&Qf[(size_t)(qbase + l31) * 64 + ks * 16 + h5 * 8];

    const int g   = t & 7;
    const int r0  = t >> 3;            // 0..31, rep adds 32
    const int swz = g ^ (r0 & 7);
    const ushort_t* baseK = Kf + (size_t)r0 * 64 + g * 8;
    const ushort_t* baseV = Vt + (size_t)r0 * 1024 + g * 8;

    v8h pk[2][2]; v8s pv[2][2];        // [set][rep]
    auto load_tile = [&](int set, int kt) {
        #pragma unroll
        for (int rep = 0; rep < 2; ++rep) {
            pk[set][rep] = *(const v8h*)(baseK + (size_t)kt * 4096 + rep * 2048);
            pv[set][rep] = *(const v8s*)(baseV + (size_t)rep * 32768 + kt * 64);
        }
    };
    auto store_tile = [&](int set) {
        #pragma unroll
        for (int rep = 0; rep < 2; ++rep) {
            int so = ((rep * 32 + r0) * 8 + swz) * 8;
            *(v8h*)&KH[so] = pk[set][rep];
            *(v8s*)&VT[so] = pv[set][rep];
        }
    };

    v16f O0 = {}, O1 = {};
    float rsumv = 0.f;

    load_tile(0, 0);
    store_tile(0);
    load_tile(1, 1);
    load_tile(0, 2);
    __syncthreads();

    for (int kt = 0; kt < 16; ++kt) {
        #pragma unroll
        for (int t2 = 0; t2 < 2; ++t2) {
            v16f s = {};
            int kvrow = t2 * 32 + l31;
            #pragma unroll
            for (int ks = 0; ks < 4; ++ks) {
                int so = (kvrow * 8 + ((ks * 2 + h5) ^ (kvrow & 7))) * 8;
                v8h khf = *(const v8h*)&KH[so];
                s = __builtin_amdgcn_mfma_f32_32x32x16_f16(khf, aq[ks], s, 0, 0, 0);
            }
            float e0[8], e1[8];
            #pragma unroll
            for (int j = 0; j < 8; ++j) {
                e0[j] = __expf(s[j] - 64.0f);
                e1[j] = __expf(s[8 + j] - 64.0f);
                rsumv += e0[j] + e1[j];
            }
            uint4 u0, u1;
            u0.x = pkbf(e0[0], e0[1]); u0.y = pkbf(e0[2], e0[3]);
            u0.z = pkbf(e0[4], e0[5]); u0.w = pkbf(e0[6], e0[7]);
            u1.x = pkbf(e1[0], e1[1]); u1.y = pkbf(e1[2], e1[3]);
            u1.z = pkbf(e1[4], e1[5]); u1.w = pkbf(e1[6], e1[7]);
            v8s p0 = __builtin_bit_cast(v8s, u0);
            v8s p1 = __builtin_bit_cast(v8s, u1);

            #pragma unroll
            for (int hh = 0; hh < 2; ++hh) {
                int rv = hh * 32 + l31;
                int g0 = (4 * t2 + h5)     ^ (rv & 7);
                int g1 = (4 * t2 + 2 + h5) ^ (rv & 7);
                v8s bv0 = *(const v8s*)&VT[(rv * 8 + g0) * 8];
                v8s bv1 = *(const v8s*)&VT[(rv * 8 + g1) * 8];
                if (hh == 0) {
                    O0 = __builtin_amdgcn_mfma_f32_32x32x16_bf16(p0, bv0, O0, 0, 0, 0);
                    O0 = __builtin_amdgcn_mfma_f32_32x32x16_bf16(p1, bv1, O0, 0, 0, 0);
                } else {
                    O1 = __builtin_amdgcn_mfma_f32_32x32x16_bf16(p0, bv0, O1, 0, 0, 0);
                    O1 = __builtin_amdgcn_mfma_f32_32x32x16_bf16(p1, bv1, O1, 0, 0, 0);
                }
            }
        }

        __syncthreads();                      // tile consumed
        if (kt < 15) {
            int set = (kt + 1) & 1;
            store_tile(set);                  // vmcnt wait: loads 2 phases old
            if (kt + 3 <= 15) load_tile(set, kt + 3);
            __syncthreads();
        }
    }

    float tot = rsumv + __shfl_xor(rsumv, 32, 64);
    if (h5 == 0) RS[w * 32 + l31] = 1.0f / tot;
    __syncthreads();
    float invr[16];
    #pragma unroll
    for (int r = 0; r < 16; ++r)
        invr[r] = RS[w * 32 + (r & 3) + 8 * (r >> 2) + 4 * h5];

    const int b    = inst >> 3;
    const int head = inst & 7;
    float* ob = out + (size_t)b * C_ * N_;
    #pragma unroll
    for (int hh = 0; hh < 2; ++hh) {
        const v16f& O = hh ? O1 : O0;
        int c = head * 64 + hh * 32 + l31;
        #pragma unroll
        for (int qd = 0; qd < 4; ++qd) {
            int n = qbase + 8 * qd + 4 * h5;
            float4 o4;
            o4.x = O[qd * 4 + 0] * invr[qd * 4 + 0];
            o4.y = O[qd * 4 + 1] * invr[qd * 4 + 1];
            o4.z = O[qd * 4 + 2] * invr[qd * 4 + 2];
            o4.w = O[qd * 4 + 3] * invr[qd * 4 + 3];
            *(float4*)&ob[(size_t)c * N_ + n] = o4;
        }
    }
}

// ---------------------------------------------------------------------------
extern "C" void kernel_launch(void* const* d_in, const int* in_sizes, int n_in,
                              void* d_out, int out_size, void* d_ws, size_t ws_size,
                              hipStream_t stream) {
    const float* x  = (const float*)d_in[0];
    const float* wq = (const float*)d_in[1];
    const float* bq = (const float*)d_in[2];
    const float* wk = (const float*)d_in[3];
    const float* bk = (const float*)d_in[4];
    const float* wv = (const float*)d_in[5];
    const float* bv = (const float*)d_in[6];
    float* out = (float*)d_out;

    char* ws = (char*)d_ws;                        // ~35 MiB used
    _Float16* wt = (_Float16*)(ws);                // 1536x512 fp16 = 1.5 MiB
    _Float16* xt = (_Float16*)(ws + 1572864);      // 8192x512 fp16 = 8 MiB
    ushort_t* qf = (ushort_t*)(ws + 9961472);      // 8 MiB fp16
    ushort_t* kf = (ushort_t*)(ws + 18350080);     // 8 MiB fp16
    ushort_t* vt = (ushort_t*)(ws + 26738688);     // 8 MiB bf16

    prep_kernel<<<dim3(16, 8, 11), 256, 0, stream>>>(
        x, wq, wk, wv, (uint_t*)wt, (uint_t*)xt);
    proj_kernel<<<dim3(128, 12), 256, 0, stream>>>(xt, wt, bq, bk, bv,
                                                   qf, kf, vt);
    attn_kernel<<<dim3(64, 8), 256, 0, stream>>>(qf, kf, vt, out);
}

// Round 10
// 140.565 us; speedup vs baseline: 1.9850x; 1.9850x over previous
//
#include <hip/hip_runtime.h>
#include <hip/hip_bf16.h>
#include <cmath>

#define B_     8
#define C_     512
#define N_     1024
#define HEADS_ 8
#define HD_    64
#define INST_  64   // B_ * HEADS_

typedef short     v8s __attribute__((ext_vector_type(8)));
typedef _Float16  v8h __attribute__((ext_vector_type(8)));
typedef float    v16f __attribute__((ext_vector_type(16)));
typedef unsigned short ushort_t;
typedef unsigned int   uint_t;

__device__ inline ushort_t f2h(float x) {
    _Float16 h = (_Float16)x;
    ushort_t r; __builtin_memcpy(&r, &h, 2); return r;
}
// packed f32x2 -> bf16x2 (v_cvt_pk_bf16_f32); low short = .x
__device__ inline uint_t pkbf(float a, float b) {
    __hip_bfloat162 p = __float22bfloat162_rn(make_float2(a, b));
    uint_t r; __builtin_memcpy(&r, &p, 4); return r;
}

// ---------------------------------------------------------------------------
// Kernel 0: unified transpose + fp16-convert prep (unchanged from R8).
// ---------------------------------------------------------------------------
__global__ __launch_bounds__(256) void prep_kernel(
    const float* __restrict__ x,
    const float* __restrict__ wq, const float* __restrict__ wk,
    const float* __restrict__ wv,
    uint_t* __restrict__ wt, uint_t* __restrict__ xt)
{
    __shared__ uint_t LH[64 * 32];
    const int z = blockIdx.z;
    const float* src;
    int srcStride;
    size_t outRow0;
    uint_t* oh;
    if (z < 3) {
        if (blockIdx.x >= 8) return;
        src = (z == 0) ? wq : (z == 1) ? wk : wv;
        srcStride = 512;
        outRow0 = (size_t)z * 512 + blockIdx.x * 64;
        oh = wt;
    } else {
        int b = z - 3;
        src = x + (size_t)b * C_ * N_;
        srcStride = 1024;
        outRow0 = (size_t)b * 1024 + blockIdx.x * 64;
        oh = xt;
    }
    const int d0 = blockIdx.x * 64;
    const int c0 = blockIdx.y * 64;
    const int t  = threadIdx.x;

    #pragma unroll
    for (int rep = 0; rep < 2; ++rep) {
        int idx = rep * 256 + t;
        int cp  = idx >> 4;
        int dq  = idx & 15;
        float4 fa = *(const float4*)&src[(size_t)(c0 + 2 * cp) * srcStride + d0 + dq * 4];
        float4 fb = *(const float4*)&src[(size_t)(c0 + 2 * cp + 1) * srcStride + d0 + dq * 4];
        float aa[4] = {fa.x, fa.y, fa.z, fa.w};
        float bb[4] = {fb.x, fb.y, fb.z, fb.w};
        #pragma unroll
        for (int j = 0; j < 4; ++j) {
            int d_l = dq * 4 + j;
            LH[d_l * 32 + (cp ^ (d_l & 31))] =
                (uint_t)f2h(aa[j]) | ((uint_t)f2h(bb[j]) << 16);
        }
    }
    __syncthreads();

    const int d_l = t >> 2;
    const int wq4 = (t & 3) * 8;
    uint_t vh[8];
    #pragma unroll
    for (int i = 0; i < 8; ++i)
        vh[i] = LH[d_l * 32 + ((wq4 + i) ^ (d_l & 31))];
    size_t base = (outRow0 + d_l) * 256 + c0 / 2 + wq4;
    *(uint4*)&oh[base]     = *(uint4*)&vh[0];
    *(uint4*)&oh[base + 4] = *(uint4*)&vh[4];
}

// ---------------------------------------------------------------------------
// Kernel 1: MFMA QKV projection, fp16. Tile 64 tok x 128 d (grid 128x12 =
// 1536 blocks, ~6/CU for TLP). Single LDS buffer + 1-deep register prefetch
// (R8's proven pipeline; NO runtime-indexed register arrays).
// ---------------------------------------------------------------------------
__global__ __launch_bounds__(256) void proj_kernel(
    const _Float16* __restrict__ xt, const _Float16* __restrict__ wt,
    const float* __restrict__ bq, const float* __restrict__ bk,
    const float* __restrict__ bv,
    ushort_t* __restrict__ qf, ushort_t* __restrict__ kf,
    ushort_t* __restrict__ vt)
{
    __shared__ _Float16 POOL[8192];    // 16 KB (main loop 12 KB; V-epi 16 KB)
    _Float16* As = POOL;               // [64 tok][4 groups x 8]
    _Float16* Bs = POOL + 2048;        // [128 d][4 groups x 8]

    const int tok0  = blockIdx.x * 64;
    const int b     = tok0 >> 10;
    const int ntb   = tok0 & 1023;
    const int by    = blockIdx.y;
    const int which = by >> 2;                       // 0=q,1=k,2=v
    const int nloc0 = (by & 3) * 128;

    const int t   = threadIdx.x;
    const int w   = t >> 6;
    const int l   = t & 63;
    const int l31 = l & 31;
    const int h5  = l >> 5;
    const int wm  = w & 1;                           // tok half (32 each)
    const int wn  = w >> 1;                          // d half (64 each)

    const int g   = t & 3;
    const int r0  = t >> 2;                          // 0..63
    const int swz = g ^ (r0 & 3);

    const _Float16* baseA = xt + (size_t)(tok0 + r0) * 512 + g * 8;
    const _Float16* baseB = wt + (size_t)(which * 512 + nloc0 + r0) * 512 + g * 8;

    v8h pfa, pfb0, pfb1;               // static names -> stay in VGPRs
    auto load_tile = [&](int k0) {
        pfa  = *(const v8h*)(baseA + k0);
        pfb0 = *(const v8h*)(baseB + k0);
        pfb1 = *(const v8h*)(baseB + 32768 + k0);    // +64 rows
    };
    auto store_tile = [&]() {
        *(v8h*)&As[(r0 * 4 + swz) * 8] = pfa;
        *(v8h*)&Bs[(r0 * 4 + swz) * 8] = pfb0;
        int row = 64 + r0;
        *(v8h*)&Bs[(row * 4 + (g ^ (row & 3))) * 8] = pfb1;
    };

    v16f acc[2] = {{}, {}};            // [ns]: 32 tok x 2x32 d

    load_tile(0);
    store_tile();
    __syncthreads();

    for (int step = 0; step < 16; ++step) {
        if (step < 15) load_tile((step + 1) * 32);   // in flight during compute

        #pragma unroll
        for (int kc = 0; kc < 2; ++kc) {
            int rm = wm * 32 + l31;
            v8h af = *(const v8h*)&As[(rm * 4 + ((kc * 2 + h5) ^ (rm & 3))) * 8];
            v8h bf[2];
            #pragma unroll
            for (int ns = 0; ns < 2; ++ns) {
                int rn = wn * 64 + ns * 32 + l31;
                bf[ns] = *(const v8h*)&Bs[(rn * 4 + ((kc * 2 + h5) ^ (rn & 3))) * 8];
            }
            #pragma unroll
            for (int ns = 0; ns < 2; ++ns)
                acc[ns] = __builtin_amdgcn_mfma_f32_32x32x16_f16(
                    af, bf[ns], acc[ns], 0, 0, 0);
        }

        __syncthreads();                      // tile consumed
        if (step < 15) {
            store_tile();                     // vmcnt wait here, post-compute
            __syncthreads();                  // writes visible
        }
    }

    // ---- epilogue ----
    if (which < 2) {
        ushort_t* oh = (which == 0) ? qf : kf;
        const float* bias = (which == 0) ? bq : bk;
        #pragma unroll
        for (int ns = 0; ns < 2; ++ns) {
            int d_local = nloc0 + wn * 64 + ns * 32 + l31;
            float bvv  = bias[d_local];
            int head   = d_local >> 6;
            int hd     = d_local & 63;
            size_t pb  = (size_t)(b * HEADS_ + head) * 65536 + hd;
            #pragma unroll
            for (int r = 0; r < 16; ++r) {
                int n = ntb + wm * 32 + (r & 3) + 8 * (r >> 2) + 4 * h5;
                oh[pb + (size_t)n * 64] = f2h(acc[ns][r] + bvv);
            }
        }
    } else {
        float bvv[2];
        #pragma unroll
        for (int ns = 0; ns < 2; ++ns)
            bvv[ns] = bv[nloc0 + wn * 64 + ns * 32 + l31];
        __syncthreads();                 // staging LDS fully consumed
        uint_t* TW = (uint_t*)POOL + w * 1024;   // wave-private 4 KB: [64 hd][16 w]
        #pragma unroll
        for (int ns = 0; ns < 2; ++ns)
            #pragma unroll
            for (int r = 0; r < 16; r += 2) {
                int tok_l = (r & 3) + 8 * (r >> 2) + 4 * h5;   // even
                int hd_l  = ns * 32 + l31;
                TW[hd_l * 16 + ((tok_l >> 1) ^ (hd_l & 15))] =
                    pkbf(acc[ns][r] + bvv[ns], acc[ns][r + 1] + bvv[ns]);
            }
        __syncthreads();
        const int head = (nloc0 + wn * 64) >> 6;
        uint_t* vtu = (uint_t*)vt;
        size_t base = (size_t)(b * HEADS_ + head) * 32768 + (size_t)l * 512
                    + (ntb + wm * 32) / 2;
        // kv-permutation baked into column order: swap bits 1<->2 of word idx
        // within each 8-word (16-token) block.
        #pragma unroll
        for (int c = 0; c < 4; ++c) {
            uint_t wd[4];
            #pragma unroll
            for (int kk = 0; kk < 4; ++kk) {
                int wsx = c * 4 + kk;
                int w3 = wsx & 7;
                int sw = (wsx & ~7) | (w3 & 1) | (((w3 >> 1) & 1) << 2)
                                   | (((w3 >> 2) & 1) << 1);
                wd[kk] = TW[l * 16 + (sw ^ (l & 15))];
            }
            *(uint4*)&vtu[base + c * 4] = *(uint4*)&wd[0];
        }
    }
}

// ---------------------------------------------------------------------------
// Kernel 2: MFMA flash attention, S^T form, fp16 QK^T + bf16 PV.
// Exact R8 structure: single buffer + 1-deep register prefetch.
// ---------------------------------------------------------------------------
__global__ __launch_bounds__(256) void attn_kernel(
    const ushort_t* __restrict__ qf, const ushort_t* __restrict__ kf,
    const ushort_t* __restrict__ vt, float* __restrict__ out)
{
    __shared__ _Float16 KH[4096];      // K tile [kv][d] fp16, swizzled
    __shared__ ushort_t VT[4096];      // V^T tile [hd][kv-perm] bf16
    __shared__ float    RS[128];

    const int inst  = blockIdx.x;
    const int chunk = blockIdx.y;
    const int t     = threadIdx.x;
    const int w     = t >> 6;
    const int l     = t & 63;
    const int l31   = l & 31;
    const int h5    = l >> 5;

    const ushort_t* Qf = qf + (size_t)inst * 65536;
    const ushort_t* Kf = kf + (size_t)inst * 65536;
    const ushort_t* Vt = vt + (size_t)inst * 65536;

    const int qbase = chunk * 128 + w * 32;

    v8h aq[4];
    #pragma unroll
    for (int ks = 0; ks < 4; ++ks)
        aq[ks] = *(const v8h*)&Qf[(size_t)(qbase + l31) * 64 + ks * 16 + h5 * 8];

    const int g   = t & 7;
    const int r0  = t >> 3;            // 0..31, rep adds 32
    const int swz = g ^ (r0 & 7);
    const ushort_t* baseK = Kf + (size_t)r0 * 64 + g * 8;
    const ushort_t* baseV = Vt + (size_t)r0 * 1024 + g * 8;

    v8h pk0, pk1; v8s pv0, pv1;        // static names -> VGPRs
    auto load_tile = [&](int kt) {
        pk0 = *(const v8h*)(baseK + (size_t)kt * 4096);
        pk1 = *(const v8h*)(baseK + (size_t)kt * 4096 + 2048);
        pv0 = *(const v8s*)(baseV + (size_t)kt * 64);
        pv1 = *(const v8s*)(baseV + 32768 + (size_t)kt * 64);
    };
    auto store_tile = [&]() {
        int so0 = (r0 * 8 + swz) * 8;
        int so1 = ((32 + r0) * 8 + swz) * 8;
        *(v8h*)&KH[so0] = pk0;
        *(v8h*)&KH[so1] = pk1;
        *(v8s*)&VT[so0] = pv0;
        *(v8s*)&VT[so1] = pv1;
    };

    v16f O0 = {}, O1 = {};
    float rsumv = 0.f;

    load_tile(0);
    store_tile();
    __syncthreads();

    for (int kt = 0; kt < 16; ++kt) {
        if (kt < 15) load_tile(kt + 1);

        #pragma unroll
        for (int t2 = 0; t2 < 2; ++t2) {
            v16f s = {};
            int kvrow = t2 * 32 + l31;
            #pragma unroll
            for (int ks = 0; ks < 4; ++ks) {
                int so = (kvrow * 8 + ((ks * 2 + h5) ^ (kvrow & 7))) * 8;
                v8h khf = *(const v8h*)&KH[so];
                s = __builtin_amdgcn_mfma_f32_32x32x16_f16(khf, aq[ks], s, 0, 0, 0);
            }
            float e0[8], e1[8];
            #pragma unroll
            for (int j = 0; j < 8; ++j) {
                e0[j] = __expf(s[j] - 64.0f);
                e1[j] = __expf(s[8 + j] - 64.0f);
                rsumv += e0[j] + e1[j];
            }
            uint4 u0, u1;
            u0.x = pkbf(e0[0], e0[1]); u0.y = pkbf(e0[2], e0[3]);
            u0.z = pkbf(e0[4], e0[5]); u0.w = pkbf(e0[6], e0[7]);
            u1.x = pkbf(e1[0], e1[1]); u1.y = pkbf(e1[2], e1[3]);
            u1.z = pkbf(e1[4], e1[5]); u1.w = pkbf(e1[6], e1[7]);
            v8s p0 = __builtin_bit_cast(v8s, u0);
            v8s p1 = __builtin_bit_cast(v8s, u1);

            #pragma unroll
            for (int hh = 0; hh < 2; ++hh) {
                int rv = hh * 32 + l31;
                int g0 = (4 * t2 + h5)     ^ (rv & 7);
                int g1 = (4 * t2 + 2 + h5) ^ (rv & 7);
                v8s bv0 = *(const v8s*)&VT[(rv * 8 + g0) * 8];
                v8s bv1 = *(const v8s*)&VT[(rv * 8 + g1) * 8];
                if (hh == 0) {
                    O0 = __builtin_amdgcn_mfma_f32_32x32x16_bf16(p0, bv0, O0, 0, 0, 0);
                    O0 = __builtin_amdgcn_mfma_f32_32x32x16_bf16(p1, bv1, O0, 0, 0, 0);
                } else {
                    O1 = __builtin_amdgcn_mfma_f32_32x32x16_bf16(p0, bv0, O1, 0, 0, 0);
                    O1 = __builtin_amdgcn_mfma_f32_32x32x16_bf16(p1, bv1, O1, 0, 0, 0);
                }
            }
        }

        __syncthreads();
        if (kt < 15) {
            store_tile();
            __syncthreads();
        }
    }

    float tot = rsumv + __shfl_xor(rsumv, 32, 64);
    if (h5 == 0) RS[w * 32 + l31] = 1.0f / tot;
    __syncthreads();
    float invr[16];
    #pragma unroll
    for (int r = 0; r < 16; ++r)
        invr[r] = RS[w * 32 + (r & 3) + 8 * (r >> 2) + 4 * h5];

    const int b    = inst >> 3;
    const int head = inst & 7;
    float* ob = out + (size_t)b * C_ * N_;
    #pragma unroll
    for (int hh = 0; hh < 2; ++hh) {
        const v16f& O = hh ? O1 : O0;
        int c = head * 64 + hh * 32 + l31;
        #pragma unroll
        for (int qd = 0; qd < 4; ++qd) {
            int n = qbase + 8 * qd + 4 * h5;
            float4 o4;
            o4.x = O[qd * 4 + 0] * invr[qd * 4 + 0];
            o4.y = O[qd * 4 + 1] * invr[qd * 4 + 1];
            o4.z = O[qd * 4 + 2] * invr[qd * 4 + 2];
            o4.w = O[qd * 4 + 3] * invr[qd * 4 + 3];
            *(float4*)&ob[(size_t)c * N_ + n] = o4;
        }
    }
}

// ---------------------------------------------------------------------------
extern "C" void kernel_launch(void* const* d_in, const int* in_sizes, int n_in,
                              void* d_out, int out_size, void* d_ws, size_t ws_size,
                              hipStream_t stream) {
    const float* x  = (const float*)d_in[0];
    const float* wq = (const float*)d_in[1];
    const float* bq = (const float*)d_in[2];
    const float* wk = (const float*)d_in[3];
    const float* bk = (const float*)d_in[4];
    const float* wv = (const float*)d_in[5];
    const float* bv = (const float*)d_in[6];
    float* out = (float*)d_out;

    char* ws = (char*)d_ws;                        // ~35 MiB used
    _Float16* wt = (_Float16*)(ws);                // 1536x512 fp16 = 1.5 MiB
    _Float16* xt = (_Float16*)(ws + 1572864);      // 8192x512 fp16 = 8 MiB
    ushort_t* qf = (ushort_t*)(ws + 9961472);      // 8 MiB fp16
    ushort_t* kf = (ushort_t*)(ws + 18350080);     // 8 MiB fp16
    ushort_t* vt = (ushort_t*)(ws + 26738688);     // 8 MiB bf16

    prep_kernel<<<dim3(16, 8, 11), 256, 0, stream>>>(
        x, wq, wk, wv, (uint_t*)wt, (uint_t*)xt);
    proj_kernel<<<dim3(128, 12), 256, 0, stream>>>(xt, wt, bq, bk, bv,
                                                   qf, kf, vt);
    attn_kernel<<<dim3(64, 8), 256, 0, stream>>>(qf, kf, vt, out);
}